// Round 13
// baseline (233.565 us; speedup 1.0000x reference)
//
#include <hip/hip_runtime.h>
#include <hip/hip_bf16.h>
#include <math.h>

typedef __attribute__((ext_vector_type(8))) short bf16x8;
typedef __attribute__((ext_vector_type(4))) short bf16x4;
typedef __attribute__((ext_vector_type(4))) float f32x4;

#define NB 4096
#define ND 1024
#define INV_T 14.2857142857142857f   // 1/0.07

__device__ inline unsigned short f2bf(float x) {
    __hip_bfloat16 h = __float2bfloat16(x);
    return *reinterpret_cast<unsigned short*>(&h);
}
__device__ inline float bf2f(unsigned short u) {
    unsigned v = ((unsigned)u) << 16;
    return __uint_as_float(v);
}
__device__ inline void gload16(const void* g, void* l) {
    __builtin_amdgcn_global_load_lds(
        (const __attribute__((address_space(1))) void*)g,
        (__attribute__((address_space(3))) void*)l, 16, 0, 0);
}

// ---------------- kernel 0: L2-normalize rows, cast to bf16 -----------------
__global__ __launch_bounds__(256) void norm_kernel(
        const float* __restrict__ M, const float* __restrict__ P,
        __hip_bfloat16* __restrict__ Mn, __hip_bfloat16* __restrict__ Pn) {
    int row = blockIdx.x & (NB - 1);
    const float* src = (blockIdx.x < NB) ? M : P;
    __hip_bfloat16* dst = (blockIdx.x < NB) ? Mn : Pn;
    int tid = threadIdx.x;
    float4 v = ((const float4*)(src + (size_t)row * ND))[tid];
    float ss = v.x * v.x + v.y * v.y + v.z * v.z + v.w * v.w;
    for (int off = 32; off; off >>= 1) ss += __shfl_down(ss, off);
    __shared__ float red[4];
    int lane = tid & 63, w = tid >> 6;
    if (lane == 0) red[w] = ss;
    __syncthreads();
    float rn = rsqrtf(red[0] + red[1] + red[2] + red[3]);
    ushort4 o;
    o.x = f2bf(v.x * rn); o.y = f2bf(v.y * rn);
    o.z = f2bf(v.z * rn); o.w = f2bf(v.w * rn);
    *(ushort4*)((unsigned short*)dst + (size_t)row * ND + tid * 4) = o;
}

// ---------------- kernel 1: per-row mask codes ------------------------------
__global__ __launch_bounds__(256) void key_kernel(
        const int* __restrict__ labels, const int* __restrict__ sm,
        const int* __restrict__ sp, int* __restrict__ code) {
    int i = blockIdx.x * 256 + threadIdx.x;
    if (i < NB) {
        int l = labels[i];
        code[i] = (l == 0) ? 0x40000000 : (1 + l + (sm[i] << 8) + (sp[i] << 16));
    }
}

// ------- kernel 2: fused row-sum + normalized masked weight matrix (bf16) ---
__global__ __launch_bounds__(256) void rowsumw_kernel(
        const float* __restrict__ cs, const int* __restrict__ code,
        unsigned short* __restrict__ W, float* __restrict__ flag) {
    int i = blockIdx.x;
    int ci = code[i];
    int tid = threadIdx.x;
    const float4* row = (const float4*)(cs + (size_t)i * NB);
    const int4* c4 = (const int4*)code;
    float4 v[4];
    int4 cj[4];
    float s = 0.f;
#pragma unroll
    for (int k = 0; k < 4; ++k) {
        int t = tid + k * 256;
        v[k] = row[t];
        cj[k] = c4[t];
        int j = t * 4;
        if (cj[k].x == ci && j + 0 != i) s += v[k].x;
        if (cj[k].y == ci && j + 1 != i) s += v[k].y;
        if (cj[k].z == ci && j + 2 != i) s += v[k].z;
        if (cj[k].w == ci && j + 3 != i) s += v[k].w;
    }
    for (int off = 1; off < 64; off <<= 1) s += __shfl_xor(s, off);
    __shared__ float red[4];
    int lane = tid & 63, w = tid >> 6;
    if (lane == 0) red[w] = s;
    __syncthreads();
    float tot = red[0] + red[1] + red[2] + red[3];
    float inv = (tot > 0.f) ? 1.f / tot : 0.f;
#pragma unroll
    for (int k = 0; k < 4; ++k) {
        int t = tid + k * 256;
        int j = t * 4;
        ushort4 o;
        o.x = (cj[k].x == ci && j + 0 != i) ? f2bf(v[k].x * inv) : (unsigned short)0;
        o.y = (cj[k].y == ci && j + 1 != i) ? f2bf(v[k].y * inv) : (unsigned short)0;
        o.z = (cj[k].z == ci && j + 2 != i) ? f2bf(v[k].z * inv) : (unsigned short)0;
        o.w = (cj[k].w == ci && j + 3 != i) ? f2bf(v[k].w * inv) : (unsigned short)0;
        *(ushort4*)&W[(size_t)i * NB + j] = o;
    }
    if (tid == 0) flag[i] = (tot > 0.f) ? 1.f : 0.f;
}

// ------- kernel 2b: in-place symmetrize W -> Wsym = W + W^T -----------------
__global__ __launch_bounds__(256) void symw_kernel(unsigned short* __restrict__ W) {
    __shared__ unsigned short Ta[64][72], Tb[64][72];
    int b = blockIdx.x;
    int ti = 0, t = b;
    while (t >= 64 - ti) { t -= 64 - ti; ++ti; }
    int tj = ti + t;
    size_t ra = (size_t)ti * 64, rb = (size_t)tj * 64;
    int tid = threadIdx.x;
    int r = tid >> 2, c0 = (tid & 3) * 16;
    int4 a0 = *(const int4*)&W[(ra + r) * NB + rb + c0];
    int4 a1 = *(const int4*)&W[(ra + r) * NB + rb + c0 + 8];
    int4 b0 = *(const int4*)&W[(rb + r) * NB + ra + c0];
    int4 b1 = *(const int4*)&W[(rb + r) * NB + ra + c0 + 8];
    *(int4*)&Ta[r][c0] = a0;  *(int4*)&Ta[r][c0 + 8] = a1;
    *(int4*)&Tb[r][c0] = b0;  *(int4*)&Tb[r][c0 + 8] = b1;
    __syncthreads();
    unsigned short oa[16], ob[16];
#pragma unroll
    for (int c = 0; c < 16; ++c) {
        int cc = c0 + c;
        oa[c] = f2bf(bf2f(Ta[r][cc]) + bf2f(Tb[cc][r]));
        ob[c] = f2bf(bf2f(Tb[r][cc]) + bf2f(Ta[cc][r]));
    }
    *(int4*)&W[(ra + r) * NB + rb + c0]     = *(int4*)&oa[0];
    *(int4*)&W[(ra + r) * NB + rb + c0 + 8] = *(int4*)&oa[8];
    *(int4*)&W[(rb + r) * NB + ra + c0]     = *(int4*)&ob[0];
    *(int4*)&W[(rb + r) * NB + ra + c0 + 8] = *(int4*)&ob[8];
}

// ---------------- kernel 3: fused 256x128-tile GEMM + loss epilogue ---------
// 1056 logical blocks (XCD-chunked, 1056 = 8*132): decode as R10-R12.
// 512 threads = 8 waves (4x2), wave tile 64x64, acc[4][4] (no-spill envelope).
// K loop: 16 tiles BK=64, THREE 48KB LDS buffers (144KB), depth-2 prefetch,
// counted vmcnt(6), ONE barrier per step (R10 STAGE/COMPUTE + R12 skeleton).
// Epilogue (Wsym): ONE 64KB tile read, d = sum(Wsym*sim).
__global__ __launch_bounds__(512) void mega_gemm(
        const __hip_bfloat16* __restrict__ Mn, const __hip_bfloat16* __restrict__ Pn,
        const unsigned short* __restrict__ Wg,
        float* __restrict__ rowsum1, float* __restrict__ colsum1,
        float* __restrict__ rowsum3, float* __restrict__ rowsum4,
        float* __restrict__ dots) {
    __shared__ char smem[147456] __attribute__((aligned(16)));

    int tid = threadIdx.x;
    int lane = tid & 63, w = tid >> 6;
    int wm = w >> 1, wn = w & 1;            // 4x2 wave grid
    int lr = lane & 15, lg = lane >> 4;

    // ---- block decode ----
    int b = (blockIdx.x & 7) * 132 + (blockIdx.x >> 3);
    int bi, bj, ch, mode;
    const __hip_bfloat16 *A, *Bm;
    if (b < 512) {
        bi = b >> 5;
        bj = (b & 31) >> 1;
        ch = b & 1;
        A = Mn; Bm = Pn; mode = 0;
    } else {
        int s = b - 512;
        int md = (s >= 272) ? 1 : 0;
        s -= md * 272;
        ch = s & 1;
        int t = s >> 1;
        bi = 0;
        while (t >= 16 - bi) { t -= 16 - bi; ++bi; }
        bj = bi + t;
        A = md ? Pn : Mn; Bm = A;
        mode = 1 + md;
    }
    bool offdiag = (bi != bj);
    size_t rowBase = (size_t)bi * 256;
    size_t colBase = (size_t)bj * 256 + ch * 128;
    float* rowTgt = (mode == 0) ? rowsum1 : ((mode == 1) ? rowsum3 : rowsum4);
    float* colTgt = (mode == 0) ? colsum1 : rowTgt;

    // ---- staging addresses (128B rows, chunk pre-swizzle ^= row&7) ----
    int sr8 = lane >> 3;                       // row within 8-row issue
    int sch = ((lane & 7) ^ sr8) * 8;          // bf16 elems (16B chunks)
    const __hip_bfloat16* gA = A + (rowBase + w * 32 + sr8) * ND + sch;
    const __hip_bfloat16* gB = Bm + (colBase + w * 16 + sr8) * ND + sch;

    f32x4 acc[4][4] = {};

    // per tile: A 256x64 (32KB, 4 issues/thread) + B 128x64 (16KB, 2 issues)
#define STAGE(bufi, t) {                                                    \
        int k0_ = (t) * 64;                                                 \
        char* baseA_ = smem + (bufi) * 49152;                               \
        char* baseB_ = baseA_ + 32768;                                      \
        _Pragma("unroll")                                                   \
        for (int c = 0; c < 4; ++c)                                         \
            gload16(gA + (size_t)c * 8 * ND + k0_, baseA_ + (w * 4 + c) * 1024); \
        _Pragma("unroll")                                                   \
        for (int c = 0; c < 2; ++c)                                         \
            gload16(gB + (size_t)c * 8 * ND + k0_, baseB_ + (w * 2 + c) * 1024); \
    }
#define COMPUTE(bufi) {                                                     \
        const __hip_bfloat16* sA = (const __hip_bfloat16*)(smem + (bufi) * 49152); \
        const __hip_bfloat16* sB = sA + 16384;                              \
        _Pragma("unroll")                                                   \
        for (int ks = 0; ks < 2; ++ks) {                                    \
            int cp = ((ks * 4 + lg) ^ (lr & 7)) * 8;                        \
            bf16x8 av[4], bv[4];                                            \
            _Pragma("unroll")                                               \
            for (int n = 0; n < 4; ++n)                                     \
                bv[n] = *(const bf16x8*)&sB[(wn * 64 + n * 16 + lr) * 64 + cp]; \
            _Pragma("unroll")                                               \
            for (int i = 0; i < 4; ++i)                                     \
                av[i] = *(const bf16x8*)&sA[(wm * 64 + i * 16 + lr) * 64 + cp]; \
            _Pragma("unroll")                                               \
            for (int i = 0; i < 4; ++i)                                     \
                _Pragma("unroll")                                           \
                for (int n = 0; n < 4; ++n)                                 \
                    acc[i][n] = __builtin_amdgcn_mfma_f32_16x16x32_bf16(    \
                        av[i], bv[n], acc[i][n], 0, 0, 0);                  \
        }                                                                   \
    }
#define BAR __builtin_amdgcn_s_barrier()

    // depth-2 pipeline over 3 buffers; buffer t%3 holds tile t. 6 loads/tile.
    STAGE(0, 0); STAGE(1, 1);                       // 12 outstanding
    asm volatile("s_waitcnt vmcnt(6)" ::: "memory"); BAR;   // tile 0 ready
    for (int t = 0; t < 14; ++t) {
        STAGE((t + 2) % 3, t + 2);    // overwrites buf computed at t-1 (safe)
        COMPUTE(t % 3);
        asm volatile("s_waitcnt vmcnt(6)" ::: "memory"); BAR;  // tile t+1 ready
    }
    COMPUTE(14 % 3);
    asm volatile("s_waitcnt vmcnt(0)" ::: "memory"); BAR;
    COMPUTE(15 % 3);
    __syncthreads();
#undef STAGE
#undef COMPUTE
#undef BAR

    // ---- epilogue: single Wsym tile (256 rows x 128 cols = 64KB) ----
    unsigned short* wl = (unsigned short*)smem;
    float d1 = 0.f;
    float cexp[4] = {0.f, 0.f, 0.f, 0.f};

#pragma unroll
    for (int c = 0; c < 8; ++c) {
        int q = w * 8 + c;                          // 0..63 (1KB issues)
        int sr = 4 * q + (lane >> 4);               // W row 0..255
        int gchunk = (lane & 15) ^ (sr & 7);        // source pre-swizzle
        gload16(Wg + (rowBase + sr) * (size_t)NB + colBase + gchunk * 8,
                smem + q * 1024);
    }
    __syncthreads();
#pragma unroll
    for (int m = 0; m < 4; ++m) {
        float rexp[4] = {0.f, 0.f, 0.f, 0.f};
#pragma unroll
        for (int n = 0; n < 4; ++n) {
            int jl = wn * 64 + n * 16 + lr;         // 0..127
#pragma unroll
            for (int r = 0; r < 4; ++r) {
                int rl = wm * 64 + m * 16 + lg * 4 + r;   // 0..255
                float sim = acc[m][n][r] * INV_T;
                float e = __expf(sim - INV_T);
                rexp[r] += e;
                cexp[n] += e;
                int ck = (jl >> 3) ^ (rl & 7);
                d1 += bf2f(wl[rl * 128 + ck * 8 + (jl & 7)]) * sim;
            }
        }
#pragma unroll
        for (int r = 0; r < 4; ++r) {
            float v = rexp[r];
            v += __shfl_xor(v, 1); v += __shfl_xor(v, 2);
            v += __shfl_xor(v, 4); v += __shfl_xor(v, 8);
            if (lr == 0)
                atomicAdd(&rowTgt[rowBase + wm * 64 + m * 16 + lg * 4 + r], v);
        }
    }

    // col-exp sums: cross always; symmetric only for offdiag supertiles
    if (mode == 0 || offdiag) {
#pragma unroll
        for (int n = 0; n < 4; ++n) {
            float v = cexp[n];
            v += __shfl_xor(v, 16); v += __shfl_xor(v, 32);
            if (lg == 0)
                atomicAdd(&colTgt[colBase + wn * 64 + n * 16 + lr], v);
        }
    }

    // weighted dot: Wsym covers (i,j)+(j,i). diag supertile counts half.
    float dtot = (mode != 0 && !offdiag) ? 0.5f * d1 : d1;
    for (int off = 32; off; off >>= 1) dtot += __shfl_xor(dtot, off);
    if (lane == 0) {
        if (mode == 0) atomicAdd(&dots[0], dtot);
        else           atomicAdd(&dots[1 + mode], dtot);
    }
}

// ---------------- kernel 4: finalize --------------------------------------
__global__ __launch_bounds__(256) void finalize_kernel(
        const float* __restrict__ rowsum1, const float* __restrict__ colsum1,
        const float* __restrict__ rowsum3, const float* __restrict__ rowsum4,
        const float* __restrict__ flag, const float* __restrict__ dots,
        float* __restrict__ out) {
    int tid = threadIdx.x;
    float l = 0.f;
    for (int i = tid; i < NB; i += 256) {
        if (flag[i] != 0.f) {
            l += 4.f * INV_T + logf(rowsum1[i]) + logf(colsum1[i]) +
                 logf(rowsum3[i]) + logf(rowsum4[i]);
        }
    }
    for (int off = 32; off; off >>= 1) l += __shfl_down(l, off);
    __shared__ float red[4];
    int lane = tid & 63, w = tid >> 6;
    if (lane == 0) red[w] = l;
    __syncthreads();
    if (tid == 0) {
        float L = red[0] + red[1] + red[2] + red[3];
        float dt = dots[0] + dots[1] + dots[2] + dots[3];
        out[0] = (L - dt) / (4.0f * (float)NB);
    }
}

extern "C" void kernel_launch(void* const* d_in, const int* in_sizes, int n_in,
                              void* d_out, int out_size, void* d_ws, size_t ws_size,
                              hipStream_t stream) {
    const float* M = (const float*)d_in[0];
    const float* P = (const float*)d_in[1];
    const int* labels = (const int*)d_in[2];
    const int* sm = (const int*)d_in[3];
    const int* sp = (const int*)d_in[4];
    const float* cs = (const float*)d_in[5];
    float* out = (float*)d_out;

    char* ws = (char*)d_ws;
    __hip_bfloat16* Mn = (__hip_bfloat16*)ws;                              // 8 MB
    __hip_bfloat16* Pn = (__hip_bfloat16*)(ws + (size_t)8 * 1024 * 1024);  // 8 MB
    unsigned short* W = (unsigned short*)(ws + (size_t)16 * 1024 * 1024);  // 32 MB
    char* p = ws + (size_t)48 * 1024 * 1024;
    int* code = (int*)p;        p += 16384;
    float* flag = (float*)p;    p += 16384;
    float* rowsum1 = (float*)p; p += 16384;
    float* colsum1 = (float*)p; p += 16384;
    float* rowsum3 = (float*)p; p += 16384;
    float* rowsum4 = (float*)p; p += 16384;
    float* dots = (float*)p;

    hipMemsetAsync(rowsum1, 0, 4 * 16384 + 256, stream);

    norm_kernel<<<2 * NB, 256, 0, stream>>>(M, P, Mn, Pn);
    key_kernel<<<NB / 256, 256, 0, stream>>>(labels, sm, sp, code);
    rowsumw_kernel<<<NB, 256, 0, stream>>>(cs, code, W, flag);
    symw_kernel<<<2080, 256, 0, stream>>>(W);

    mega_gemm<<<1056, 512, 0, stream>>>(Mn, Pn, W, rowsum1, colsum1,
                                        rowsum3, rowsum4, dots);

    finalize_kernel<<<1, 256, 0, stream>>>(rowsum1, colsum1, rowsum3, rowsum4,
                                           flag, dots, out);
}

// Round 14
// 217.343 us; speedup vs baseline: 1.0746x; 1.0746x over previous
//
#include <hip/hip_runtime.h>
#include <hip/hip_bf16.h>
#include <math.h>

typedef __attribute__((ext_vector_type(8))) short bf16x8;
typedef __attribute__((ext_vector_type(4))) short bf16x4;
typedef __attribute__((ext_vector_type(4))) float f32x4;

#define NB 4096
#define ND 1024
#define INV_T 14.2857142857142857f   // 1/0.07

__device__ inline unsigned short f2bf(float x) {
    __hip_bfloat16 h = __float2bfloat16(x);
    return *reinterpret_cast<unsigned short*>(&h);
}
__device__ inline float bf2f(unsigned short u) {
    unsigned v = ((unsigned)u) << 16;
    return __uint_as_float(v);
}
__device__ inline void gload16(const void* g, void* l) {
    __builtin_amdgcn_global_load_lds(
        (const __attribute__((address_space(1))) void*)g,
        (__attribute__((address_space(3))) void*)l, 16, 0, 0);
}

// ---------------- kernel 0: L2-normalize rows, cast to fp8 e4m3 -------------
__global__ __launch_bounds__(256) void norm_kernel(
        const float* __restrict__ M, const float* __restrict__ P,
        unsigned char* __restrict__ Mf, unsigned char* __restrict__ Pf) {
    int row = blockIdx.x & (NB - 1);
    const float* src = (blockIdx.x < NB) ? M : P;
    unsigned char* dst = (blockIdx.x < NB) ? Mf : Pf;
    int tid = threadIdx.x;
    float4 v = ((const float4*)(src + (size_t)row * ND))[tid];
    float ss = v.x * v.x + v.y * v.y + v.z * v.z + v.w * v.w;
    for (int off = 32; off; off >>= 1) ss += __shfl_down(ss, off);
    __shared__ float red[4];
    int lane = tid & 63, w = tid >> 6;
    if (lane == 0) red[w] = ss;
    __syncthreads();
    float rn = rsqrtf(red[0] + red[1] + red[2] + red[3]);
    int p = __builtin_amdgcn_cvt_pk_fp8_f32(v.x * rn, v.y * rn, 0, false);
    p = __builtin_amdgcn_cvt_pk_fp8_f32(v.z * rn, v.w * rn, p, true);
    ((int*)dst)[row * 256 + tid] = p;
}

// ---------------- kernel 1: per-row mask codes ------------------------------
__global__ __launch_bounds__(256) void key_kernel(
        const int* __restrict__ labels, const int* __restrict__ sm,
        const int* __restrict__ sp, int* __restrict__ code) {
    int i = blockIdx.x * 256 + threadIdx.x;
    if (i < NB) {
        int l = labels[i];
        code[i] = (l == 0) ? 0x40000000 : (1 + l + (sm[i] << 8) + (sp[i] << 16));
    }
}

// ------- kernel 2: fused row-sum + normalized masked weight matrix (bf16) ---
__global__ __launch_bounds__(256) void rowsumw_kernel(
        const float* __restrict__ cs, const int* __restrict__ code,
        unsigned short* __restrict__ W, float* __restrict__ flag) {
    int i = blockIdx.x;
    int ci = code[i];
    int tid = threadIdx.x;
    const float4* row = (const float4*)(cs + (size_t)i * NB);
    const int4* c4 = (const int4*)code;
    float4 v[4];
    int4 cj[4];
    float s = 0.f;
#pragma unroll
    for (int k = 0; k < 4; ++k) {
        int t = tid + k * 256;
        v[k] = row[t];
        cj[k] = c4[t];
        int j = t * 4;
        if (cj[k].x == ci && j + 0 != i) s += v[k].x;
        if (cj[k].y == ci && j + 1 != i) s += v[k].y;
        if (cj[k].z == ci && j + 2 != i) s += v[k].z;
        if (cj[k].w == ci && j + 3 != i) s += v[k].w;
    }
    for (int off = 1; off < 64; off <<= 1) s += __shfl_xor(s, off);
    __shared__ float red[4];
    int lane = tid & 63, w = tid >> 6;
    if (lane == 0) red[w] = s;
    __syncthreads();
    float tot = red[0] + red[1] + red[2] + red[3];
    float inv = (tot > 0.f) ? 1.f / tot : 0.f;
#pragma unroll
    for (int k = 0; k < 4; ++k) {
        int t = tid + k * 256;
        int j = t * 4;
        ushort4 o;
        o.x = (cj[k].x == ci && j + 0 != i) ? f2bf(v[k].x * inv) : (unsigned short)0;
        o.y = (cj[k].y == ci && j + 1 != i) ? f2bf(v[k].y * inv) : (unsigned short)0;
        o.z = (cj[k].z == ci && j + 2 != i) ? f2bf(v[k].z * inv) : (unsigned short)0;
        o.w = (cj[k].w == ci && j + 3 != i) ? f2bf(v[k].w * inv) : (unsigned short)0;
        *(ushort4*)&W[(size_t)i * NB + j] = o;
    }
    if (tid == 0) flag[i] = (tot > 0.f) ? 1.f : 0.f;
}

// ------- kernel 2b: in-place symmetrize W -> Wsym = W + W^T -----------------
__global__ __launch_bounds__(256) void symw_kernel(unsigned short* __restrict__ W) {
    __shared__ unsigned short Ta[64][72], Tb[64][72];
    int b = blockIdx.x;
    int ti = 0, t = b;
    while (t >= 64 - ti) { t -= 64 - ti; ++ti; }
    int tj = ti + t;
    size_t ra = (size_t)ti * 64, rb = (size_t)tj * 64;
    int tid = threadIdx.x;
    int r = tid >> 2, c0 = (tid & 3) * 16;
    int4 a0 = *(const int4*)&W[(ra + r) * NB + rb + c0];
    int4 a1 = *(const int4*)&W[(ra + r) * NB + rb + c0 + 8];
    int4 b0 = *(const int4*)&W[(rb + r) * NB + ra + c0];
    int4 b1 = *(const int4*)&W[(rb + r) * NB + ra + c0 + 8];
    *(int4*)&Ta[r][c0] = a0;  *(int4*)&Ta[r][c0 + 8] = a1;
    *(int4*)&Tb[r][c0] = b0;  *(int4*)&Tb[r][c0 + 8] = b1;
    __syncthreads();
    unsigned short oa[16], ob[16];
#pragma unroll
    for (int c = 0; c < 16; ++c) {
        int cc = c0 + c;
        oa[c] = f2bf(bf2f(Ta[r][cc]) + bf2f(Tb[cc][r]));
        ob[c] = f2bf(bf2f(Tb[r][cc]) + bf2f(Ta[cc][r]));
    }
    *(int4*)&W[(ra + r) * NB + rb + c0]     = *(int4*)&oa[0];
    *(int4*)&W[(ra + r) * NB + rb + c0 + 8] = *(int4*)&oa[8];
    *(int4*)&W[(rb + r) * NB + ra + c0]     = *(int4*)&ob[0];
    *(int4*)&W[(rb + r) * NB + ra + c0 + 8] = *(int4*)&ob[8];
}

// ---------------- kernel 3: fused fp8 256x128-tile GEMM + loss epilogue -----
// 1056 logical blocks (XCD-chunked, 1056 = 8*132): decode as R10-R13.
// 512 threads = 8 waves (4x2), wave tile 64x64, acc[4][4] (no-spill envelope).
// K loop: 16 tiles BK=64 fp8 (rows 64B), FOUR 24KB LDS buffers, depth-3
// prefetch, counted vmcnt(6), ONE barrier per step. Staged bytes halved vs
// bf16 (the measured ~140cy/KB staging limit is the bottleneck).
// LDS swizzle (2-way free): 16B chunk ^= (row&3)^((row>>2)&3), both sides.
// Epilogue (Wsym bf16): ONE 64KB tile read, d = sum(Wsym*sim).
__global__ __launch_bounds__(512) void mega_gemm(
        const unsigned char* __restrict__ Mf, const unsigned char* __restrict__ Pf,
        const unsigned short* __restrict__ Wg,
        float* __restrict__ rowsum1, float* __restrict__ colsum1,
        float* __restrict__ rowsum3, float* __restrict__ rowsum4,
        float* __restrict__ dots) {
    __shared__ char smem[98304] __attribute__((aligned(16)));

    int tid = threadIdx.x;
    int lane = tid & 63, w = tid >> 6;
    int wm = w >> 1, wn = w & 1;            // 4x2 wave grid
    int lr = lane & 15, lg = lane >> 4;

    // ---- block decode ----
    int b = (blockIdx.x & 7) * 132 + (blockIdx.x >> 3);
    int bi, bj, ch, mode;
    const unsigned char *A, *Bm;
    if (b < 512) {
        bi = b >> 5;
        bj = (b & 31) >> 1;
        ch = b & 1;
        A = Mf; Bm = Pf; mode = 0;
    } else {
        int s = b - 512;
        int md = (s >= 272) ? 1 : 0;
        s -= md * 272;
        ch = s & 1;
        int t = s >> 1;
        bi = 0;
        while (t >= 16 - bi) { t -= 16 - bi; ++bi; }
        bj = bi + t;
        A = md ? Pf : Mf; Bm = A;
        mode = 1 + md;
    }
    bool offdiag = (bi != bj);
    size_t rowBase = (size_t)bi * 256;
    size_t colBase = (size_t)bj * 256 + ch * 128;
    float* rowTgt = (mode == 0) ? rowsum1 : ((mode == 1) ? rowsum3 : rowsum4);
    float* colTgt = (mode == 0) ? colsum1 : rowTgt;

    // ---- staging addresses: 64B fp8 rows, 4 lanes/row, pre-swizzled chunk --
    int sr = lane >> 2;                        // row 0..15 within 1KB unit
    int scs = (lane & 3) ^ (sr & 3) ^ ((sr >> 2) & 3);   // 16B chunk
    const unsigned char* gA = A + (rowBase + w * 32 + sr) * ND + scs * 16;
    const unsigned char* gB = Bm + (colBase + w * 16 + sr) * ND + scs * 16;

    f32x4 acc[4][4] = {};

    // per tile: A 256x64B (16KB, 2 units/wave) + B 128x64B (8KB, 1 unit/wave)
#define STAGE(bufi, t) {                                                    \
        int k0_ = (t) * 64;                                                 \
        char* baseA_ = smem + (bufi) * 24576;                               \
        char* baseB_ = baseA_ + 16384;                                      \
        gload16(gA + k0_,                  baseA_ + (w * 2    ) * 1024);    \
        gload16(gA + (size_t)16 * ND + k0_, baseA_ + (w * 2 + 1) * 1024);   \
        gload16(gB + k0_,                  baseB_ + w * 1024);              \
    }
#define COMPUTE(bufi) {                                                     \
        const unsigned char* sA = (const unsigned char*)(smem + (bufi) * 24576); \
        const unsigned char* sB = sA + 16384;                               \
        int rx = (lr & 3) ^ ((lr >> 2) & 3);                                \
        _Pragma("unroll")                                                   \
        for (int ks = 0; ks < 2; ++ks) {                                    \
            int cp = (((ks * 2) + (lg >> 1)) ^ rx) * 16 + (lg & 1) * 8;     \
            long av[4], bv[4];                                              \
            _Pragma("unroll")                                               \
            for (int n = 0; n < 4; ++n)                                     \
                bv[n] = *(const long*)&sB[(wn * 64 + n * 16 + lr) * 64 + cp]; \
            _Pragma("unroll")                                               \
            for (int i = 0; i < 4; ++i)                                     \
                av[i] = *(const long*)&sA[(wm * 64 + i * 16 + lr) * 64 + cp]; \
            _Pragma("unroll")                                               \
            for (int i = 0; i < 4; ++i)                                     \
                _Pragma("unroll")                                           \
                for (int n = 0; n < 4; ++n)                                 \
                    acc[i][n] = __builtin_amdgcn_mfma_f32_16x16x32_fp8_fp8( \
                        av[i], bv[n], acc[i][n], 0, 0, 0);                  \
        }                                                                   \
    }
#define BAR __builtin_amdgcn_s_barrier()

    // depth-3 pipeline over 4 buffers; buffer t&3 holds tile t. 3 loads/tile.
    STAGE(0, 0); STAGE(1, 1); STAGE(2, 2);          // 9 outstanding
    asm volatile("s_waitcnt vmcnt(6)" ::: "memory"); BAR;   // tile 0 ready
    for (int t = 0; t < 13; ++t) {
        STAGE((t + 3) & 3, t + 3);
        COMPUTE(t & 3);
        asm volatile("s_waitcnt vmcnt(6)" ::: "memory"); BAR;  // tile t+1 ready
    }
    COMPUTE(13 & 3);
    asm volatile("s_waitcnt vmcnt(3)" ::: "memory"); BAR;
    COMPUTE(14 & 3);
    asm volatile("s_waitcnt vmcnt(0)" ::: "memory"); BAR;
    COMPUTE(15 & 3);
    __syncthreads();
#undef STAGE
#undef COMPUTE
#undef BAR

    // ---- epilogue: single Wsym tile (256 rows x 128 cols = 64KB, bf16) ----
    unsigned short* wl = (unsigned short*)smem;
    float d1 = 0.f;
    float cexp[4] = {0.f, 0.f, 0.f, 0.f};

#pragma unroll
    for (int c = 0; c < 8; ++c) {
        int q = w * 8 + c;                          // 0..63 (1KB issues)
        int sw = 4 * q + (lane >> 4);               // W row 0..255
        int gchunk = (lane & 15) ^ (sw & 7);        // source pre-swizzle
        gload16(Wg + (rowBase + sw) * (size_t)NB + colBase + gchunk * 8,
                smem + q * 1024);
    }
    __syncthreads();
#pragma unroll
    for (int m = 0; m < 4; ++m) {
        float rexp[4] = {0.f, 0.f, 0.f, 0.f};
#pragma unroll
        for (int n = 0; n < 4; ++n) {
            int jl = wn * 64 + n * 16 + lr;         // 0..127
#pragma unroll
            for (int r = 0; r < 4; ++r) {
                int rl = wm * 64 + m * 16 + lg * 4 + r;   // 0..255
                float sim = acc[m][n][r] * INV_T;
                float e = __expf(sim - INV_T);
                rexp[r] += e;
                cexp[n] += e;
                int ck = (jl >> 3) ^ (rl & 7);
                d1 += bf2f(wl[rl * 128 + ck * 8 + (jl & 7)]) * sim;
            }
        }
#pragma unroll
        for (int r = 0; r < 4; ++r) {
            float v = rexp[r];
            v += __shfl_xor(v, 1); v += __shfl_xor(v, 2);
            v += __shfl_xor(v, 4); v += __shfl_xor(v, 8);
            if (lr == 0)
                atomicAdd(&rowTgt[rowBase + wm * 64 + m * 16 + lg * 4 + r], v);
        }
    }

    // col-exp sums: cross always; symmetric only for offdiag supertiles
    if (mode == 0 || offdiag) {
#pragma unroll
        for (int n = 0; n < 4; ++n) {
            float v = cexp[n];
            v += __shfl_xor(v, 16); v += __shfl_xor(v, 32);
            if (lg == 0)
                atomicAdd(&colTgt[colBase + wn * 64 + n * 16 + lr], v);
        }
    }

    // weighted dot: Wsym covers (i,j)+(j,i). diag supertile counts half.
    float dtot = (mode != 0 && !offdiag) ? 0.5f * d1 : d1;
    for (int off = 32; off; off >>= 1) dtot += __shfl_xor(dtot, off);
    if (lane == 0) {
        if (mode == 0) atomicAdd(&dots[0], dtot);
        else           atomicAdd(&dots[1 + mode], dtot);
    }
}

// ---------------- kernel 4: finalize --------------------------------------
__global__ __launch_bounds__(256) void finalize_kernel(
        const float* __restrict__ rowsum1, const float* __restrict__ colsum1,
        const float* __restrict__ rowsum3, const float* __restrict__ rowsum4,
        const float* __restrict__ flag, const float* __restrict__ dots,
        float* __restrict__ out) {
    int tid = threadIdx.x;
    float l = 0.f;
    for (int i = tid; i < NB; i += 256) {
        if (flag[i] != 0.f) {
            l += 4.f * INV_T + logf(rowsum1[i]) + logf(colsum1[i]) +
                 logf(rowsum3[i]) + logf(rowsum4[i]);
        }
    }
    for (int off = 32; off; off >>= 1) l += __shfl_down(l, off);
    __shared__ float red[4];
    int lane = tid & 63, w = tid >> 6;
    if (lane == 0) red[w] = l;
    __syncthreads();
    if (tid == 0) {
        float L = red[0] + red[1] + red[2] + red[3];
        float dt = dots[0] + dots[1] + dots[2] + dots[3];
        out[0] = (L - dt) / (4.0f * (float)NB);
    }
}

extern "C" void kernel_launch(void* const* d_in, const int* in_sizes, int n_in,
                              void* d_out, int out_size, void* d_ws, size_t ws_size,
                              hipStream_t stream) {
    const float* M = (const float*)d_in[0];
    const float* P = (const float*)d_in[1];
    const int* labels = (const int*)d_in[2];
    const int* sm = (const int*)d_in[3];
    const int* sp = (const int*)d_in[4];
    const float* cs = (const float*)d_in[5];
    float* out = (float*)d_out;

    char* ws = (char*)d_ws;
    unsigned char* Mf = (unsigned char*)ws;                                // 4 MB
    unsigned char* Pf = (unsigned char*)(ws + (size_t)4 * 1024 * 1024);    // 4 MB
    unsigned short* W = (unsigned short*)(ws + (size_t)16 * 1024 * 1024);  // 32 MB
    char* p = ws + (size_t)48 * 1024 * 1024;
    int* code = (int*)p;        p += 16384;
    float* flag = (float*)p;    p += 16384;
    float* rowsum1 = (float*)p; p += 16384;
    float* colsum1 = (float*)p; p += 16384;
    float* rowsum3 = (float*)p; p += 16384;
    float* rowsum4 = (float*)p; p += 16384;
    float* dots = (float*)p;

    hipMemsetAsync(rowsum1, 0, 4 * 16384 + 256, stream);

    norm_kernel<<<2 * NB, 256, 0, stream>>>(M, P, Mf, Pf);
    key_kernel<<<NB / 256, 256, 0, stream>>>(labels, sm, sp, code);
    rowsumw_kernel<<<NB, 256, 0, stream>>>(cs, code, W, flag);
    symw_kernel<<<2080, 256, 0, stream>>>(W);

    mega_gemm<<<1056, 512, 0, stream>>>(Mf, Pf, W, rowsum1, colsum1,
                                        rowsum3, rowsum4, dots);

    finalize_kernel<<<1, 256, 0, stream>>>(rowsum1, colsum1, rowsum3, rowsum4,
                                           flag, dots, out);
}

// Round 15
// 208.265 us; speedup vs baseline: 1.1215x; 1.0436x over previous
//
#include <hip/hip_runtime.h>
#include <hip/hip_bf16.h>
#include <math.h>

typedef __attribute__((ext_vector_type(8))) short bf16x8;
typedef __attribute__((ext_vector_type(4))) short bf16x4;
typedef __attribute__((ext_vector_type(4))) float f32x4;

#define NB 4096
#define ND 1024
#define INV_T 14.2857142857142857f   // 1/0.07

__device__ inline unsigned short f2bf(float x) {
    __hip_bfloat16 h = __float2bfloat16(x);
    return *reinterpret_cast<unsigned short*>(&h);
}
__device__ inline float bf2f(unsigned short u) {
    unsigned v = ((unsigned)u) << 16;
    return __uint_as_float(v);
}
__device__ inline void gload16(const void* g, void* l) {
    __builtin_amdgcn_global_load_lds(
        (const __attribute__((address_space(1))) void*)g,
        (__attribute__((address_space(3))) void*)l, 16, 0, 0);
}

// ---------------- kernel 0: L2-normalize rows, cast to fp8 e4m3 -------------
__global__ __launch_bounds__(256) void norm_kernel(
        const float* __restrict__ M, const float* __restrict__ P,
        unsigned char* __restrict__ Mf, unsigned char* __restrict__ Pf) {
    int row = blockIdx.x & (NB - 1);
    const float* src = (blockIdx.x < NB) ? M : P;
    unsigned char* dst = (blockIdx.x < NB) ? Mf : Pf;
    int tid = threadIdx.x;
    float4 v = ((const float4*)(src + (size_t)row * ND))[tid];
    float ss = v.x * v.x + v.y * v.y + v.z * v.z + v.w * v.w;
    for (int off = 32; off; off >>= 1) ss += __shfl_down(ss, off);
    __shared__ float red[4];
    int lane = tid & 63, w = tid >> 6;
    if (lane == 0) red[w] = ss;
    __syncthreads();
    float rn = rsqrtf(red[0] + red[1] + red[2] + red[3]);
    int p = __builtin_amdgcn_cvt_pk_fp8_f32(v.x * rn, v.y * rn, 0, false);
    p = __builtin_amdgcn_cvt_pk_fp8_f32(v.z * rn, v.w * rn, p, true);
    ((int*)dst)[row * 256 + tid] = p;
}

// ---------------- kernel 1: per-row mask codes ------------------------------
__global__ __launch_bounds__(256) void key_kernel(
        const int* __restrict__ labels, const int* __restrict__ sm,
        const int* __restrict__ sp, int* __restrict__ code) {
    int i = blockIdx.x * 256 + threadIdx.x;
    if (i < NB) {
        int l = labels[i];
        code[i] = (l == 0) ? 0x40000000 : (1 + l + (sm[i] << 8) + (sp[i] << 16));
    }
}

// ------- kernel 2: fused row-sum + normalized masked weight matrix (bf16) ---
__global__ __launch_bounds__(256) void rowsumw_kernel(
        const float* __restrict__ cs, const int* __restrict__ code,
        unsigned short* __restrict__ W, float* __restrict__ flag) {
    int i = blockIdx.x;
    int ci = code[i];
    int tid = threadIdx.x;
    const float4* row = (const float4*)(cs + (size_t)i * NB);
    const int4* c4 = (const int4*)code;
    float4 v[4];
    int4 cj[4];
    float s = 0.f;
#pragma unroll
    for (int k = 0; k < 4; ++k) {
        int t = tid + k * 256;
        v[k] = row[t];
        cj[k] = c4[t];
        int j = t * 4;
        if (cj[k].x == ci && j + 0 != i) s += v[k].x;
        if (cj[k].y == ci && j + 1 != i) s += v[k].y;
        if (cj[k].z == ci && j + 2 != i) s += v[k].z;
        if (cj[k].w == ci && j + 3 != i) s += v[k].w;
    }
    for (int off = 1; off < 64; off <<= 1) s += __shfl_xor(s, off);
    __shared__ float red[4];
    int lane = tid & 63, w = tid >> 6;
    if (lane == 0) red[w] = s;
    __syncthreads();
    float tot = red[0] + red[1] + red[2] + red[3];
    float inv = (tot > 0.f) ? 1.f / tot : 0.f;
#pragma unroll
    for (int k = 0; k < 4; ++k) {
        int t = tid + k * 256;
        int j = t * 4;
        ushort4 o;
        o.x = (cj[k].x == ci && j + 0 != i) ? f2bf(v[k].x * inv) : (unsigned short)0;
        o.y = (cj[k].y == ci && j + 1 != i) ? f2bf(v[k].y * inv) : (unsigned short)0;
        o.z = (cj[k].z == ci && j + 2 != i) ? f2bf(v[k].z * inv) : (unsigned short)0;
        o.w = (cj[k].w == ci && j + 3 != i) ? f2bf(v[k].w * inv) : (unsigned short)0;
        *(ushort4*)&W[(size_t)i * NB + j] = o;
    }
    if (tid == 0) flag[i] = (tot > 0.f) ? 1.f : 0.f;
}

// ------- kernel 2b: in-place symmetrize W -> Wsym = W + W^T -----------------
__global__ __launch_bounds__(256) void symw_kernel(unsigned short* __restrict__ W) {
    __shared__ unsigned short Ta[64][72], Tb[64][72];
    int b = blockIdx.x;
    int ti = 0, t = b;
    while (t >= 64 - ti) { t -= 64 - ti; ++ti; }
    int tj = ti + t;
    size_t ra = (size_t)ti * 64, rb = (size_t)tj * 64;
    int tid = threadIdx.x;
    int r = tid >> 2, c0 = (tid & 3) * 16;
    int4 a0 = *(const int4*)&W[(ra + r) * NB + rb + c0];
    int4 a1 = *(const int4*)&W[(ra + r) * NB + rb + c0 + 8];
    int4 b0 = *(const int4*)&W[(rb + r) * NB + ra + c0];
    int4 b1 = *(const int4*)&W[(rb + r) * NB + ra + c0 + 8];
    *(int4*)&Ta[r][c0] = a0;  *(int4*)&Ta[r][c0 + 8] = a1;
    *(int4*)&Tb[r][c0] = b0;  *(int4*)&Tb[r][c0 + 8] = b1;
    __syncthreads();
    unsigned short oa[16], ob[16];
#pragma unroll
    for (int c = 0; c < 16; ++c) {
        int cc = c0 + c;
        oa[c] = f2bf(bf2f(Ta[r][cc]) + bf2f(Tb[cc][r]));
        ob[c] = f2bf(bf2f(Tb[r][cc]) + bf2f(Ta[cc][r]));
    }
    *(int4*)&W[(ra + r) * NB + rb + c0]     = *(int4*)&oa[0];
    *(int4*)&W[(ra + r) * NB + rb + c0 + 8] = *(int4*)&oa[8];
    *(int4*)&W[(rb + r) * NB + ra + c0]     = *(int4*)&ob[0];
    *(int4*)&W[(rb + r) * NB + ra + c0 + 8] = *(int4*)&ob[8];
}

// ---------------- kernel 3: fused fp8 128x128-tile GEMM + loss epilogue -----
// 2080 logical blocks (XCD-chunked, 2080 = 8*260):
//   b < 1024: cross S1 = Mf Pf^T, 32x32 grid.
//   b >= 1024: symmetric (Mf then Pf), upper-tri 528 each.
// 256 threads = 4 waves (2x2), wave tile 64x64, acc[4][4].
// Occupancy play: fp8 operands (16 VGPR) + acc 64 AGPR + ~100 arch <= 170
// -> __launch_bounds__(256,3) pins 3 waves/EU -> THREE blocks/CU overlap
// (m97/m114 mechanism) to hide the per-step staging latency that capped
// all 1-block/CU variants (R10-R14) at ~5.6K cy/step.
// K loop: 16 tiles BK=64 fp8, THREE 16KB LDS buffers, depth-2, vmcnt(4),
// one barrier/step. Epilogue: 32KB Wsym tile (bf16). LDS total 48KB.
__global__ __launch_bounds__(256, 3) void mega_gemm(
        const unsigned char* __restrict__ Mf, const unsigned char* __restrict__ Pf,
        const unsigned short* __restrict__ Wg,
        float* __restrict__ rowsum1, float* __restrict__ colsum1,
        float* __restrict__ rowsum3, float* __restrict__ rowsum4,
        float* __restrict__ dots) {
    __shared__ char smem[49152] __attribute__((aligned(16)));

    int tid = threadIdx.x;
    int lane = tid & 63, w = tid >> 6;      // w: 0..3
    int wm = w >> 1, wn = w & 1;            // 2x2 wave grid
    int lr = lane & 15, lg = lane >> 4;

    // ---- block decode ----
    int b = (blockIdx.x & 7) * 260 + (blockIdx.x >> 3);
    int bi, bj, mode;
    const unsigned char *A, *Bm;
    if (b < 1024) {
        bi = b >> 5;
        bj = b & 31;
        A = Mf; Bm = Pf; mode = 0;
    } else {
        int s = b - 1024;
        int md = (s >= 528) ? 1 : 0;
        s -= md * 528;
        bi = 0;
        while (s >= 32 - bi) { s -= 32 - bi; ++bi; }
        bj = bi + s;
        A = md ? Pf : Mf; Bm = A;
        mode = 1 + md;
    }
    bool offdiag = (bi != bj);
    size_t rowBase = (size_t)bi * 128;
    size_t colBase = (size_t)bj * 128;
    float* rowTgt = (mode == 0) ? rowsum1 : ((mode == 1) ? rowsum3 : rowsum4);
    float* colTgt = (mode == 0) ? colsum1 : rowTgt;

    // ---- staging addresses: 64B fp8 rows, 4 lanes/row, pre-swizzled chunk --
    int sr = lane >> 2;                        // row 0..15 within 1KB unit
    int scs = (lane & 3) ^ (sr & 3) ^ ((sr >> 2) & 3);   // 16B chunk
    const unsigned char* gA = A + (rowBase + w * 32 + sr) * ND + scs * 16;
    const unsigned char* gB = Bm + (colBase + w * 32 + sr) * ND + scs * 16;

    f32x4 acc[4][4] = {};

    // per tile: A 128x64B (8KB) + B 128x64B (8KB); 4 x 1KB units per wave
#define STAGE(bufi, t) {                                                    \
        int k0_ = (t) * 64;                                                 \
        char* baseA_ = smem + (bufi) * 16384;                               \
        char* baseB_ = baseA_ + 8192;                                       \
        gload16(gA + k0_,                   baseA_ + (w * 2    ) * 1024);   \
        gload16(gA + (size_t)16 * ND + k0_, baseA_ + (w * 2 + 1) * 1024);   \
        gload16(gB + k0_,                   baseB_ + (w * 2    ) * 1024);   \
        gload16(gB + (size_t)16 * ND + k0_, baseB_ + (w * 2 + 1) * 1024);   \
    }
#define COMPUTE(bufi) {                                                     \
        const unsigned char* sA = (const unsigned char*)(smem + (bufi) * 16384); \
        const unsigned char* sB = sA + 8192;                                \
        int rx = (lr & 3) ^ ((lr >> 2) & 3);                                \
        _Pragma("unroll")                                                   \
        for (int ks = 0; ks < 2; ++ks) {                                    \
            int cp = (((ks * 2) + (lg >> 1)) ^ rx) * 16 + (lg & 1) * 8;     \
            long av[4], bv[4];                                              \
            _Pragma("unroll")                                               \
            for (int n = 0; n < 4; ++n)                                     \
                bv[n] = *(const long*)&sB[(wn * 64 + n * 16 + lr) * 64 + cp]; \
            _Pragma("unroll")                                               \
            for (int i = 0; i < 4; ++i)                                     \
                av[i] = *(const long*)&sA[(wm * 64 + i * 16 + lr) * 64 + cp]; \
            _Pragma("unroll")                                               \
            for (int i = 0; i < 4; ++i)                                     \
                _Pragma("unroll")                                           \
                for (int n = 0; n < 4; ++n)                                 \
                    acc[i][n] = __builtin_amdgcn_mfma_f32_16x16x32_fp8_fp8( \
                        av[i], bv[n], acc[i][n], 0, 0, 0);                  \
        }                                                                   \
    }
#define BAR __builtin_amdgcn_s_barrier()

    // depth-2 pipeline over 3 buffers; buffer t%3 holds tile t. 4 loads/step.
    STAGE(0, 0); STAGE(1, 1);                       // 8 outstanding
    asm volatile("s_waitcnt vmcnt(4)" ::: "memory"); BAR;   // tile 0 ready
    for (int t = 0; t < 14; ++t) {
        STAGE((t + 2) % 3, t + 2);    // overwrites buf computed at t-1 (safe)
        COMPUTE(t % 3);
        asm volatile("s_waitcnt vmcnt(4)" ::: "memory"); BAR;  // tile t+1 ready
    }
    COMPUTE(14 % 3);
    asm volatile("s_waitcnt vmcnt(0)" ::: "memory"); BAR;
    COMPUTE(15 % 3);
    __syncthreads();
#undef STAGE
#undef COMPUTE
#undef BAR

    // ---- epilogue: single Wsym tile (128 rows x 128 cols = 32KB, bf16) ----
    unsigned short* wl = (unsigned short*)smem;
    float d1 = 0.f;
    float cexp[4] = {0.f, 0.f, 0.f, 0.f};

#pragma unroll
    for (int c = 0; c < 8; ++c) {
        int q = w * 8 + c;                          // 0..31 (1KB issues)
        int sw = 4 * q + (lane >> 4);               // W row 0..127
        int gchunk = (lane & 15) ^ (sw & 7);        // source pre-swizzle
        gload16(Wg + (rowBase + sw) * (size_t)NB + colBase + gchunk * 8,
                smem + q * 1024);
    }
    __syncthreads();
#pragma unroll
    for (int m = 0; m < 4; ++m) {
        float rexp[4] = {0.f, 0.f, 0.f, 0.f};
#pragma unroll
        for (int n = 0; n < 4; ++n) {
            int jl = wn * 64 + n * 16 + lr;         // 0..127
#pragma unroll
            for (int r = 0; r < 4; ++r) {
                int rl = wm * 64 + m * 16 + lg * 4 + r;   // 0..127
                float sim = acc[m][n][r] * INV_T;
                float e = __expf(sim - INV_T);
                rexp[r] += e;
                cexp[n] += e;
                int ck = (jl >> 3) ^ (rl & 7);
                d1 += bf2f(wl[rl * 128 + ck * 8 + (jl & 7)]) * sim;
            }
        }
#pragma unroll
        for (int r = 0; r < 4; ++r) {
            float v = rexp[r];
            v += __shfl_xor(v, 1); v += __shfl_xor(v, 2);
            v += __shfl_xor(v, 4); v += __shfl_xor(v, 8);
            if (lr == 0)
                atomicAdd(&rowTgt[rowBase + wm * 64 + m * 16 + lg * 4 + r], v);
        }
    }

    // col-exp sums: cross always; symmetric only for offdiag tiles
    if (mode == 0 || offdiag) {
#pragma unroll
        for (int n = 0; n < 4; ++n) {
            float v = cexp[n];
            v += __shfl_xor(v, 16); v += __shfl_xor(v, 32);
            if (lg == 0)
                atomicAdd(&colTgt[colBase + wn * 64 + n * 16 + lr], v);
        }
    }

    // weighted dot: Wsym covers (i,j)+(j,i). diag tile counts half.
    float dtot = (mode != 0 && !offdiag) ? 0.5f * d1 : d1;
    for (int off = 32; off; off >>= 1) dtot += __shfl_xor(dtot, off);
    if (lane == 0) {
        if (mode == 0) atomicAdd(&dots[0], dtot);
        else           atomicAdd(&dots[1 + mode], dtot);
    }
}

// ---------------- kernel 4: finalize --------------------------------------
__global__ __launch_bounds__(256) void finalize_kernel(
        const float* __restrict__ rowsum1, const float* __restrict__ colsum1,
        const float* __restrict__ rowsum3, const float* __restrict__ rowsum4,
        const float* __restrict__ flag, const float* __restrict__ dots,
        float* __restrict__ out) {
    int tid = threadIdx.x;
    float l = 0.f;
    for (int i = tid; i < NB; i += 256) {
        if (flag[i] != 0.f) {
            l += 4.f * INV_T + logf(rowsum1[i]) + logf(colsum1[i]) +
                 logf(rowsum3[i]) + logf(rowsum4[i]);
        }
    }
    for (int off = 32; off; off >>= 1) l += __shfl_down(l, off);
    __shared__ float red[4];
    int lane = tid & 63, w = tid >> 6;
    if (lane == 0) red[w] = l;
    __syncthreads();
    if (tid == 0) {
        float L = red[0] + red[1] + red[2] + red[3];
        float dt = dots[0] + dots[1] + dots[2] + dots[3];
        out[0] = (L - dt) / (4.0f * (float)NB);
    }
}

extern "C" void kernel_launch(void* const* d_in, const int* in_sizes, int n_in,
                              void* d_out, int out_size, void* d_ws, size_t ws_size,
                              hipStream_t stream) {
    const float* M = (const float*)d_in[0];
    const float* P = (const float*)d_in[1];
    const int* labels = (const int*)d_in[2];
    const int* sm = (const int*)d_in[3];
    const int* sp = (const int*)d_in[4];
    const float* cs = (const float*)d_in[5];
    float* out = (float*)d_out;

    char* ws = (char*)d_ws;
    unsigned char* Mf = (unsigned char*)ws;                                // 4 MB
    unsigned char* Pf = (unsigned char*)(ws + (size_t)4 * 1024 * 1024);    // 4 MB
    unsigned short* W = (unsigned short*)(ws + (size_t)16 * 1024 * 1024);  // 32 MB
    char* p = ws + (size_t)48 * 1024 * 1024;
    int* code = (int*)p;        p += 16384;
    float* flag = (float*)p;    p += 16384;
    float* rowsum1 = (float*)p; p += 16384;
    float* colsum1 = (float*)p; p += 16384;
    float* rowsum3 = (float*)p; p += 16384;
    float* rowsum4 = (float*)p; p += 16384;
    float* dots = (float*)p;

    hipMemsetAsync(rowsum1, 0, 4 * 16384 + 256, stream);

    norm_kernel<<<2 * NB, 256, 0, stream>>>(M, P, Mf, Pf);
    key_kernel<<<NB / 256, 256, 0, stream>>>(labels, sm, sp, code);
    rowsumw_kernel<<<NB, 256, 0, stream>>>(cs, code, W, flag);
    symw_kernel<<<2080, 256, 0, stream>>>(W);

    mega_gemm<<<2080, 256, 0, stream>>>(Mf, Pf, W, rowsum1, colsum1,
                                        rowsum3, rowsum4, dots);

    finalize_kernel<<<1, 256, 0, stream>>>(rowsum1, colsum1, rowsum3, rowsum4,
                                           flag, dots, out);
}